// Round 9
// baseline (442.121 us; speedup 1.0000x reference)
//
#include <hip/hip_runtime.h>
#include <math.h>

#define N 1024
#define NM1 1023
#define DIM 128
#define LAMB 0.9f
#define INV2SIG2 (1.0f / 450.0f)   // 0.5 / sigma^2, sigma=15
#define MITERS 14                  // Aitken-extrapolated Neumann chain length
#define NB 256                     // persistent grid: 256 blocks == 256 CUs

typedef short v8s __attribute__((ext_vector_type(8)));
typedef float v4f __attribute__((ext_vector_type(4)));

__device__ __forceinline__ unsigned short f2bf(float x) {   // RNE float->bf16
    unsigned int u = __float_as_uint(x);
    u += 0x7FFFu + ((u >> 16) & 1u);
    return (unsigned short)(u >> 16);
}
__device__ __forceinline__ float bf2f(unsigned short h) {
    return __uint_as_float(((unsigned int)h) << 16);
}
__device__ __forceinline__ v8s cvt8(const float* p) {      // 8 fp32 -> v8s bf16
    v8s r;
    #pragma unroll
    for (int i = 0; i < 8; ++i) r[i] = (short)f2bf(p[i]);
    return r;
}

// soft grid barrier: one counter per barrier id (memset to 0 before launch).
// release: __syncthreads (block stores drained) + __threadfence + atomicAdd;
// acquire: spin on device-scope atomic, then __threadfence + __syncthreads.
__device__ __forceinline__ void gridbar(unsigned int* bars, int id) {
    __syncthreads();
    if (threadIdx.x == 0) {
        __threadfence();
        atomicAdd(&bars[id], 1u);
        while (atomicAdd(&bars[id], 0u) < (unsigned)NB)
            __builtin_amdgcn_s_sleep(2);
        __threadfence();
    }
    __syncthreads();
}

__global__ __launch_bounds__(256) void k_mega(
    const float* __restrict__ f,
    const float* __restrict__ w1, const float* __restrict__ b1,
    const float* __restrict__ w2, const float* __restrict__ b2,
    const float* __restrict__ w3, const float* __restrict__ b3,
    const float* __restrict__ w4, const float* __restrict__ b4,
    unsigned int* bars, float* total, float* fn2, float* mag,
    float* S, float* R, float* t1v, float* t2v, float* bboth, float* A0,
    float* zA, float* zb0, float* zb1, float* zb2,
    unsigned short* xb, unsigned short* Bu,
    float* out)
{
    __shared__ float red4[4];
    __shared__ float bvalS;
    __shared__ float ush[1024];

    const int b = blockIdx.x, t = threadIdx.x;
    const int wave = t >> 6, lane = t & 63;
    const int l15 = lane & 15, quad = lane >> 4;

    // ================= phase 0: compose_a (S=W3*W2 | R=W1*W4 | t1,t2) =================
    if (b < 64) {
        const int i = 2 * b + (t >> 7), j = t & 127;
        float acc = 0.f;
        #pragma unroll 8
        for (int k = 0; k < 128; ++k) acc += w3[i * 128 + k] * w2[k * 128 + j];
        S[i * 128 + j] = acc;
    } else if (b < 128) {
        const int i = 2 * (b - 64) + (t >> 7), j = t & 127;
        float acc = 0.f;
        #pragma unroll 8
        for (int k = 0; k < 128; ++k) acc += w1[i * 128 + k] * w4[k * 128 + j];
        R[i * 128 + j] = acc;
    } else if (b == 128) {
        if (t < 128) {                  // t1 = W3 b2 + b3
            float acc = b3[t];
            #pragma unroll 8
            for (int k = 0; k < 128; ++k) acc += w3[t * 128 + k] * b2[k];
            t1v[t] = acc;
        } else {                        // t2 = W1 b4
            const int i = t - 128;
            float acc = 0.f;
            #pragma unroll 8
            for (int k = 0; k < 128; ++k) acc += w1[i * 128 + k] * b4[k];
            t2v[i] = acc;
        }
    }
    gridbar(bars, 0);

    // ================= phase 1: compose_b (G=W4*S | X=R*S | biases), fp32 S reuse ======
    if (b < 64) {                       // G rows 0-127 of Wboth -> write into S? no: reuse R? keep in 'S' slot? write to Wb region = reuse t-areas... use S as W output would clobber inputs. Use dedicated region: store G/X into R after read? R still needed for X. Write results into 'S'-adjacent region via pointer Wb passed as S+... simplest: results go to A0-adjacent scratch? We write into 'S' region AFTER all reads? Not safe across blocks. Use separate buffer: reuse zA..? too small. => We write into 'Bu' head (16 KB) as fp32 scratch via cast.
        float* Wb = (float*)Bu;         // 32768 fp32 scratch (Bu written later, phase 3)
        const int i = 2 * b + (t >> 7), j = t & 127;
        float acc = 0.f;
        #pragma unroll 8
        for (int k = 0; k < 128; ++k) acc += w4[i * 128 + k] * S[k * 128 + j];
        Wb[i * 128 + j] = acc;
    } else if (b < 128) {
        float* Wb = (float*)Bu;
        const int i = 2 * (b - 64) + (t >> 7), j = t & 127;
        float acc = 0.f;
        #pragma unroll 8
        for (int k = 0; k < 128; ++k) acc += R[i * 128 + k] * S[k * 128 + j];
        Wb[(128 + i) * 128 + j] = acc;
    } else if (b == 128) {
        if (t < 128) {                  // bg = W4 t1 + b4
            float acc = b4[t];
            #pragma unroll 8
            for (int k = 0; k < 128; ++k) acc += w4[t * 128 + k] * t1v[k];
            bboth[t] = acc;
        } else {                        // bx = R t1 + t2 + b1
            const int i = t - 128;
            float acc = t2v[i] + b1[i];
            #pragma unroll 8
            for (int k = 0; k < 128; ++k) acc += R[i * 128 + k] * t1v[k];
            bboth[128 + i] = acc;
        }
    }
    gridbar(bars, 1);

    // ================= phase 2: MFMA gemm Y = f @ Wb^T + bboth; xb, fn2, mag ==========
    {
        const float* Wb = (const float*)Bu;
        const int i0 = (b >> 4) * 64;       // 16 row-tiles of 64
        const int j0 = (b & 15) * 16;       // 16 col-tiles of 16 (over 256 outputs)
        const int ri = i0 + wave * 16;
        const float* ap = f  + (ri + l15) * 128 + quad * 8;
        const float* bp = Wb + (j0 + l15) * 128 + quad * 8;
        v4f acc = {0.f, 0.f, 0.f, 0.f};
        #pragma unroll
        for (int kc = 0; kc < 4; ++kc) {
            v8s a  = cvt8(ap + kc * 32);
            v8s bb = cvt8(bp + kc * 32);
            acc = __builtin_amdgcn_mfma_f32_16x16x32_bf16(a, bb, acc, 0, 0, 0);
        }
        const float bias = bboth[j0 + l15];
        const bool isx = (j0 >= 128);
        float sq[4];
        #pragma unroll
        for (int reg = 0; reg < 4; ++reg) {
            float yv = acc[reg] + bias;
            sq[reg] = yv * yv;
            if (isx) xb[(ri + quad * 4 + reg) * DIM + (j0 - 128) + l15] = f2bf(yv);
        }
        #pragma unroll
        for (int reg = 0; reg < 4; ++reg) {
            float ss = sq[reg];
            ss += __shfl_xor(ss, 1, 64); ss += __shfl_xor(ss, 2, 64);
            ss += __shfl_xor(ss, 4, 64); ss += __shfl_xor(ss, 8, 64);
            if (l15 == 0)
                atomicAdd((isx ? mag : fn2) + (ri + quad * 4 + reg), ss);
        }
    }
    gridbar(bars, 2);

    // ================= phase 3: affinity -> Bu (unscaled bf16), totals, A0 ============
    {
        const int slab = b >> 2;            // 0..63: rows slab*16..+16
        const int qtr  = b & 3;             // j-quarter
        const int i0 = slab * 16;
        const unsigned short* ap = xb + (i0 + l15) * DIM + quad * 8;
        v8s afr[4];
        #pragma unroll
        for (int kc = 0; kc < 4; ++kc) afr[kc] = *(const v8s*)(ap + kc * 32);

        float rowsum[4] = {0.f, 0.f, 0.f, 0.f};
        #pragma unroll
        for (int s = 0; s < 4; ++s) {
            const int j0 = (qtr * 16 + wave * 4 + s) * 16;
            const unsigned short* bp = xb + (j0 + l15) * DIM + quad * 8;
            v4f acc = {0.f, 0.f, 0.f, 0.f};
            #pragma unroll
            for (int kc = 0; kc < 4; ++kc)
                acc = __builtin_amdgcn_mfma_f32_16x16x32_bf16(
                          afr[kc], *(const v8s*)(bp + kc * 32), acc, 0, 0, 0);
            const int gj = j0 + l15;
            const float rm = 1.0f / mag[gj];
            const float fj = fn2[gj] * INV2SIG2;
            #pragma unroll
            for (int reg = 0; reg < 4; ++reg) {
                const int gi = i0 + quad * 4 + reg;
                float Sv = acc[reg] * rm - 1.0f;
                float a = (gi == gj) ? 0.f : __expf(-(Sv * Sv) * fj);
                Bu[gi * N + gj] = f2bf(a);
                rowsum[reg] += a;
                if (gi == 0) A0[gj] = a;    // fp32 row 0 for exact-ish P0
            }
        }
        #pragma unroll
        for (int reg = 0; reg < 4; ++reg) {
            float ss = rowsum[reg];
            ss += __shfl_xor(ss, 1, 64); ss += __shfl_xor(ss, 2, 64);
            ss += __shfl_xor(ss, 4, 64); ss += __shfl_xor(ss, 8, 64);
            if (l15 == 0) atomicAdd(&total[i0 + quad * 4 + reg], ss);
        }
    }
    gridbar(bars, 3);

    // ================= phase 4: per-row constants + z0 = P0 ===========================
    const int r = b * 4 + wave;             // one row per wave, 1024 waves
    float rscale, p0r;
    {
        const float tot0 = fmaxf(total[0], 1e-10f);
        const float totr = fmaxf(total[r], 1e-10f);
        rscale = (r == 0) ? 0.f : LAMB / totr;   // folds B = lambda*A/total_r
        p0r    = (r == 0) ? 0.f : A0[r] / tot0;
        if (lane == 0) zA[r] = p0r;
    }
    gridbar(bars, 4);

    // ================= phase 5: 14 Neumann iterations z <- P0 + B z ===================
    float* zbuf[3] = {zb0, zb1, zb2};
    const float* zprev = zA;
    for (int it = 0; it < MITERS; ++it) {
        float* znext = zbuf[it % 3];
        const uint4*  m4 = (const uint4*)(Bu + r * N + lane * 16);
        const float4* z4 = (const float4*)(zprev + lane * 16);
        uint4 ma = m4[0], mb = m4[1];
        float4 z0 = z4[0], z1 = z4[1], z2 = z4[2], z3 = z4[3];
        float acc = 0.f;
        acc += bf2f((unsigned short)(ma.x)) * z0.x + bf2f((unsigned short)(ma.x >> 16)) * z0.y;
        acc += bf2f((unsigned short)(ma.y)) * z0.z + bf2f((unsigned short)(ma.y >> 16)) * z0.w;
        acc += bf2f((unsigned short)(ma.z)) * z1.x + bf2f((unsigned short)(ma.z >> 16)) * z1.y;
        acc += bf2f((unsigned short)(ma.w)) * z1.z + bf2f((unsigned short)(ma.w >> 16)) * z1.w;
        acc += bf2f((unsigned short)(mb.x)) * z2.x + bf2f((unsigned short)(mb.x >> 16)) * z2.y;
        acc += bf2f((unsigned short)(mb.y)) * z2.z + bf2f((unsigned short)(mb.y >> 16)) * z2.w;
        acc += bf2f((unsigned short)(mb.z)) * z3.x + bf2f((unsigned short)(mb.z >> 16)) * z3.y;
        acc += bf2f((unsigned short)(mb.w)) * z3.z + bf2f((unsigned short)(mb.w >> 16)) * z3.w;
        #pragma unroll
        for (int off = 32; off >= 1; off >>= 1) acc += __shfl_xor(acc, off, 64);
        if (lane == 0) znext[r] = p0r + rscale * acc;
        gridbar(bars, 5 + it);
        zprev = znext;
    }

    // ================= epilogue (block 0): Aitken + center/relu/softmax ===============
    if (b != 0) return;
    {
        const float* zM  = zbuf[(MITERS - 1) % 3];
        const float* zM1 = zbuf[(MITERS - 2) % 3];
        const float* zM2 = zbuf[(MITERS - 3) % 3];
        float av[4], d1v[4];
        float s12 = 0.f, s22 = 0.f;
        #pragma unroll
        for (int k = 0; k < 4; ++k) {
            const int e = t + 256 * k;
            av[k] = zM[e];
            float bb = zM1[e], cc = zM2[e];
            d1v[k] = av[k] - bb;
            float d2 = bb - cc;
            s12 += d1v[k] * d2;
            s22 += d2 * d2;
        }
        // block reduce s12
        #pragma unroll
        for (int off = 32; off >= 1; off >>= 1) s12 += __shfl_down(s12, off, 64);
        if (lane == 0) red4[wave] = s12;
        __syncthreads();
        if (t == 0) bvalS = red4[0] + red4[1] + red4[2] + red4[3];
        __syncthreads();
        const float dot12 = bvalS;
        __syncthreads();
        #pragma unroll
        for (int off = 32; off >= 1; off >>= 1) s22 += __shfl_down(s22, off, 64);
        if (lane == 0) red4[wave] = s22;
        __syncthreads();
        if (t == 0) bvalS = red4[0] + red4[1] + red4[2] + red4[3];
        __syncthreads();
        const float dot22 = bvalS;
        __syncthreads();

        float lam = dot12 / fmaxf(dot22, 1e-30f);
        lam = fminf(fmaxf(lam, 0.0f), 0.95f);
        const float coef = lam / (1.0f - lam);
        #pragma unroll
        for (int k = 0; k < 4; ++k) ush[t + 256 * k] = av[k] + coef * d1v[k];
        __syncthreads();

        float Pv[4];
        float ps = 0.f;
        #pragma unroll
        for (int k = 0; k < 4; ++k) {
            const int e = t + 256 * k;
            Pv[k] = (e >= 1) ? 0.1f * ush[e] : 0.f;
            ps += Pv[k];
        }
        #pragma unroll
        for (int off = 32; off >= 1; off >>= 1) ps += __shfl_down(ps, off, 64);
        if (lane == 0) red4[wave] = ps;
        __syncthreads();
        if (t == 0) bvalS = (red4[0] + red4[1] + red4[2] + red4[3]) / 1023.0f;
        __syncthreads();
        const float mean = bvalS;
        __syncthreads();

        float mx = 0.f;   // relu'd values >= 0, so 0 is a safe identity
        #pragma unroll
        for (int k = 0; k < 4; ++k) {
            const int e = t + 256 * k;
            if (e >= 1) {
                Pv[k] = fmaxf(Pv[k] - mean, 0.f) * 100.f;
                mx = fmaxf(mx, Pv[k]);
            }
        }
        #pragma unroll
        for (int off = 32; off >= 1; off >>= 1) mx = fmaxf(mx, __shfl_down(mx, off, 64));
        if (lane == 0) red4[wave] = mx;
        __syncthreads();
        if (t == 0) bvalS = fmaxf(fmaxf(red4[0], red4[1]), fmaxf(red4[2], red4[3]));
        __syncthreads();
        const float gmax = bvalS;
        __syncthreads();

        float Ev[4];
        float es = 0.f;
        #pragma unroll
        for (int k = 0; k < 4; ++k) {
            const int e = t + 256 * k;
            Ev[k] = (e >= 1) ? expf(Pv[k] - gmax) : 0.f;
            es += Ev[k];
        }
        #pragma unroll
        for (int off = 32; off >= 1; off >>= 1) es += __shfl_down(es, off, 64);
        if (lane == 0) red4[wave] = es;
        __syncthreads();
        if (t == 0) bvalS = red4[0] + red4[1] + red4[2] + red4[3];
        __syncthreads();
        const float esum = bvalS;
        #pragma unroll
        for (int k = 0; k < 4; ++k) {
            const int e = t + 256 * k;
            if (e >= 1) out[e - 1] = Ev[k] / esum;
        }
    }
}

extern "C" void kernel_launch(void* const* d_in, const int* in_sizes, int n_in,
                              void* d_out, int out_size, void* d_ws, size_t ws_size,
                              hipStream_t stream) {
    const float* f  = (const float*)d_in[0];
    const float* w1 = (const float*)d_in[1];
    const float* b1 = (const float*)d_in[2];
    const float* w2 = (const float*)d_in[3];
    const float* b2 = (const float*)d_in[4];
    const float* w3 = (const float*)d_in[5];
    const float* b3 = (const float*)d_in[6];
    const float* w4 = (const float*)d_in[7];
    const float* b4 = (const float*)d_in[8];
    float* ws = (float*)d_ws;

    // float-unit offsets
    unsigned int* bars = (unsigned int*)ws;                 // 64 counters
    float* total = ws + 64;                                 // 1024
    float* fn2   = ws + 1088;                               // 1024
    float* mag   = ws + 2112;                               // 1024
    float* S     = ws + 3136;                               // 16384
    float* R     = ws + 19520;                              // 16384
    float* t1v   = ws + 35904;                              // 128
    float* t2v   = ws + 36032;                              // 128
    float* bboth = ws + 36160;                              // 256
    float* A0    = ws + 36416;                              // 1024
    float* zA    = ws + 37440;                              // 1024
    float* zb0   = ws + 38464;                              // 1024
    float* zb1   = ws + 39488;                              // 1024
    float* zb2   = ws + 40512;                              // 1024
    unsigned short* xb = (unsigned short*)(ws + 41536);     // 65536 floats
    unsigned short* Bu = (unsigned short*)(ws + 107072);    // 524288 floats
    float* out = (float*)d_out;

    // zero barrier counters + total/fn2/mag in one memset (graph-capture safe)
    hipMemsetAsync(ws, 0, (64 + 3 * 1024) * sizeof(float), stream);

    k_mega<<<NB, 256, 0, stream>>>(f, w1, b1, w2, b2, w3, b3, w4, b4,
                                   bars, total, fn2, mag,
                                   S, R, t1v, t2v, bboth, A0,
                                   zA, zb0, zb1, zb2, xb, Bu, out);
}

// Round 10
// 401.619 us; speedup vs baseline: 1.1008x; 1.1008x over previous
//
#include <hip/hip_runtime.h>
#include <math.h>

#define N 1024
#define NM1 1023
#define DIM 128
#define LAMB 0.9f
#define INV2SIG2 (1.0f / 450.0f)   // 0.5 / sigma^2, sigma=15
#define MITERS 14                  // Aitken-extrapolated Neumann chain length
#define NB 256                     // persistent grid: 256 blocks == 256 CUs

typedef short v8s __attribute__((ext_vector_type(8)));
typedef float v4f __attribute__((ext_vector_type(4)));

__device__ __forceinline__ unsigned short f2bf(float x) {   // RNE float->bf16
    unsigned int u = __float_as_uint(x);
    u += 0x7FFFu + ((u >> 16) & 1u);
    return (unsigned short)(u >> 16);
}
__device__ __forceinline__ float bf2f(unsigned short h) {
    return __uint_as_float(((unsigned int)h) << 16);
}
__device__ __forceinline__ v8s cvt8(const float* p) {      // 8 fp32 -> v8s bf16
    v8s r;
    #pragma unroll
    for (int i = 0; i < 8; ++i) r[i] = (short)f2bf(p[i]);
    return r;
}

// soft grid barrier, one counter per id. Arrive = single RMW (release, agent);
// wait = LOAD spin (acquire, agent) + sleep backoff. Round 9 spun on atomicAdd
// RMWs -> ~18us/barrier from same-line RMW serialization; load spin broadcasts.
__device__ __forceinline__ void gridbar(unsigned int* bars, int id) {
    __syncthreads();
    if (threadIdx.x == 0) {
        __hip_atomic_fetch_add(&bars[id], 1u, __ATOMIC_RELEASE,
                               __HIP_MEMORY_SCOPE_AGENT);
        while (__hip_atomic_load(&bars[id], __ATOMIC_ACQUIRE,
                                 __HIP_MEMORY_SCOPE_AGENT) < (unsigned)NB)
            __builtin_amdgcn_s_sleep(4);
        __threadfence();
    }
    __syncthreads();
}

__global__ __launch_bounds__(256) void k_mega(
    const float* __restrict__ f,
    const float* __restrict__ w1, const float* __restrict__ b1,
    const float* __restrict__ w2, const float* __restrict__ b2,
    const float* __restrict__ w3, const float* __restrict__ b3,
    const float* __restrict__ w4, const float* __restrict__ b4,
    unsigned int* bars, float* total, float* fn2, float* mag,
    float* S, float* R, float* t1v, float* t2v, float* bboth, float* A0,
    float* zb0, float* zb1, float* zb2,
    unsigned short* xb, unsigned short* Bu,
    float* out)
{
    __shared__ float red4[4];
    __shared__ float bvalS;
    __shared__ float ush[1024];

    const int b = blockIdx.x, t = threadIdx.x;
    const int wave = t >> 6, lane = t & 63;
    const int l15 = lane & 15, quad = lane >> 4;

    // ================= phase 0: compose_a (S=W3*W2 | R=W1*W4 | t1,t2) =================
    if (b < 64) {
        const int i = 2 * b + (t >> 7), j = t & 127;
        float acc = 0.f;
        #pragma unroll 8
        for (int k = 0; k < 128; ++k) acc += w3[i * 128 + k] * w2[k * 128 + j];
        S[i * 128 + j] = acc;
    } else if (b < 128) {
        const int i = 2 * (b - 64) + (t >> 7), j = t & 127;
        float acc = 0.f;
        #pragma unroll 8
        for (int k = 0; k < 128; ++k) acc += w1[i * 128 + k] * w4[k * 128 + j];
        R[i * 128 + j] = acc;
    } else if (b == 128) {
        if (t < 128) {                  // t1 = W3 b2 + b3
            float acc = b3[t];
            #pragma unroll 8
            for (int k = 0; k < 128; ++k) acc += w3[t * 128 + k] * b2[k];
            t1v[t] = acc;
        } else {                        // t2 = W1 b4
            const int i = t - 128;
            float acc = 0.f;
            #pragma unroll 8
            for (int k = 0; k < 128; ++k) acc += w1[i * 128 + k] * b4[k];
            t2v[i] = acc;
        }
    }
    gridbar(bars, 0);

    // ================= phase 1: compose_b -> Wb (fp32 scratch in Bu head) =============
    if (b < 64) {
        float* Wb = (float*)Bu;         // 32768 fp32 scratch (Bu proper written phase 3)
        const int i = 2 * b + (t >> 7), j = t & 127;
        float acc = 0.f;
        #pragma unroll 8
        for (int k = 0; k < 128; ++k) acc += w4[i * 128 + k] * S[k * 128 + j];
        Wb[i * 128 + j] = acc;
    } else if (b < 128) {
        float* Wb = (float*)Bu;
        const int i = 2 * (b - 64) + (t >> 7), j = t & 127;
        float acc = 0.f;
        #pragma unroll 8
        for (int k = 0; k < 128; ++k) acc += R[i * 128 + k] * S[k * 128 + j];
        Wb[(128 + i) * 128 + j] = acc;
    } else if (b == 128) {
        if (t < 128) {                  // bg = W4 t1 + b4
            float acc = b4[t];
            #pragma unroll 8
            for (int k = 0; k < 128; ++k) acc += w4[t * 128 + k] * t1v[k];
            bboth[t] = acc;
        } else {                        // bx = R t1 + t2 + b1
            const int i = t - 128;
            float acc = t2v[i] + b1[i];
            #pragma unroll 8
            for (int k = 0; k < 128; ++k) acc += R[i * 128 + k] * t1v[k];
            bboth[128 + i] = acc;
        }
    }
    gridbar(bars, 1);

    // ================= phase 2: MFMA gemm Y = f @ Wb^T + bboth; xb, fn2, mag ==========
    {
        const float* Wb = (const float*)Bu;
        const int i0 = (b >> 4) * 64;       // 16 row-tiles of 64
        const int j0 = (b & 15) * 16;       // 16 col-tiles of 16 (over 256 outputs)
        const int ri = i0 + wave * 16;
        const float* ap = f  + (ri + l15) * 128 + quad * 8;
        const float* bp = Wb + (j0 + l15) * 128 + quad * 8;
        v4f acc = {0.f, 0.f, 0.f, 0.f};
        #pragma unroll
        for (int kc = 0; kc < 4; ++kc) {
            v8s a  = cvt8(ap + kc * 32);
            v8s bb = cvt8(bp + kc * 32);
            acc = __builtin_amdgcn_mfma_f32_16x16x32_bf16(a, bb, acc, 0, 0, 0);
        }
        const float bias = bboth[j0 + l15];
        const bool isx = (j0 >= 128);
        float sq[4];
        #pragma unroll
        for (int reg = 0; reg < 4; ++reg) {
            float yv = acc[reg] + bias;
            sq[reg] = yv * yv;
            if (isx) xb[(ri + quad * 4 + reg) * DIM + (j0 - 128) + l15] = f2bf(yv);
        }
        #pragma unroll
        for (int reg = 0; reg < 4; ++reg) {
            float ss = sq[reg];
            ss += __shfl_xor(ss, 1, 64); ss += __shfl_xor(ss, 2, 64);
            ss += __shfl_xor(ss, 4, 64); ss += __shfl_xor(ss, 8, 64);
            if (l15 == 0)
                atomicAdd((isx ? mag : fn2) + (ri + quad * 4 + reg), ss);
        }
    }
    gridbar(bars, 2);

    // ================= phase 3: affinity -> Bu (unscaled bf16), totals, A0 ============
    {
        const int slab = b >> 2;            // rows slab*16..+16
        const int qtr  = b & 3;             // j-quarter
        const int i0 = slab * 16;
        const unsigned short* ap = xb + (i0 + l15) * DIM + quad * 8;
        v8s afr[4];
        #pragma unroll
        for (int kc = 0; kc < 4; ++kc) afr[kc] = *(const v8s*)(ap + kc * 32);

        float rowsum[4] = {0.f, 0.f, 0.f, 0.f};
        #pragma unroll
        for (int s = 0; s < 4; ++s) {
            const int j0 = (qtr * 16 + wave * 4 + s) * 16;
            const unsigned short* bp = xb + (j0 + l15) * DIM + quad * 8;
            v4f acc = {0.f, 0.f, 0.f, 0.f};
            #pragma unroll
            for (int kc = 0; kc < 4; ++kc)
                acc = __builtin_amdgcn_mfma_f32_16x16x32_bf16(
                          afr[kc], *(const v8s*)(bp + kc * 32), acc, 0, 0, 0);
            const int gj = j0 + l15;
            const float rm = 1.0f / mag[gj];
            const float fj = fn2[gj] * INV2SIG2;
            #pragma unroll
            for (int reg = 0; reg < 4; ++reg) {
                const int gi = i0 + quad * 4 + reg;
                float Sv = acc[reg] * rm - 1.0f;
                float a = (gi == gj) ? 0.f : __expf(-(Sv * Sv) * fj);
                Bu[gi * N + gj] = f2bf(a);
                rowsum[reg] += a;
                if (gi == 0) A0[gj] = a;    // fp32 row 0 for P0
            }
        }
        #pragma unroll
        for (int reg = 0; reg < 4; ++reg) {
            float ss = rowsum[reg];
            ss += __shfl_xor(ss, 1, 64); ss += __shfl_xor(ss, 2, 64);
            ss += __shfl_xor(ss, 4, 64); ss += __shfl_xor(ss, 8, 64);
            if (l15 == 0) atomicAdd(&total[i0 + quad * 4 + reg], ss);
        }
    }
    gridbar(bars, 3);

    // ================= phase 4: 14 Neumann iterations z <- P0 + B z ===================
    // it==0 reads A0 (z0 = P0 = A0*r0s, scale hoisted out of the dot product).
    const int r = b * 4 + wave;             // one row per wave, 1024 waves
    const float r0s = 1.0f / fmaxf(total[0], 1e-10f);
    const float rscale = (r == 0) ? 0.f : LAMB / fmaxf(total[r], 1e-10f);
    const float p0r    = (r == 0) ? 0.f : A0[r] * r0s;

    float* zbuf[3] = {zb0, zb1, zb2};
    const float* zprev = A0;
    for (int it = 0; it < MITERS; ++it) {
        const float zscale = (it == 0) ? r0s : 1.0f;
        float* znext = zbuf[it % 3];
        const uint4*  m4 = (const uint4*)(Bu + r * N + lane * 16);
        const float4* z4 = (const float4*)(zprev + lane * 16);
        uint4 ma = m4[0], mb = m4[1];
        float4 z0 = z4[0], z1 = z4[1], z2 = z4[2], z3 = z4[3];
        float acc = 0.f;
        acc += bf2f((unsigned short)(ma.x)) * z0.x + bf2f((unsigned short)(ma.x >> 16)) * z0.y;
        acc += bf2f((unsigned short)(ma.y)) * z0.z + bf2f((unsigned short)(ma.y >> 16)) * z0.w;
        acc += bf2f((unsigned short)(ma.z)) * z1.x + bf2f((unsigned short)(ma.z >> 16)) * z1.y;
        acc += bf2f((unsigned short)(ma.w)) * z1.z + bf2f((unsigned short)(ma.w >> 16)) * z1.w;
        acc += bf2f((unsigned short)(mb.x)) * z2.x + bf2f((unsigned short)(mb.x >> 16)) * z2.y;
        acc += bf2f((unsigned short)(mb.y)) * z2.z + bf2f((unsigned short)(mb.y >> 16)) * z2.w;
        acc += bf2f((unsigned short)(mb.z)) * z3.x + bf2f((unsigned short)(mb.z >> 16)) * z3.y;
        acc += bf2f((unsigned short)(mb.w)) * z3.z + bf2f((unsigned short)(mb.w >> 16)) * z3.w;
        #pragma unroll
        for (int off = 32; off >= 1; off >>= 1) acc += __shfl_xor(acc, off, 64);
        if (lane == 0) znext[r] = p0r + rscale * zscale * acc;
        gridbar(bars, 4 + it);
        zprev = znext;
    }

    // ================= epilogue (block 0): Aitken + center/relu/softmax ===============
    if (b != 0) return;
    {
        const float* zM  = zbuf[(MITERS - 1) % 3];
        const float* zM1 = zbuf[(MITERS - 2) % 3];
        const float* zM2 = zbuf[(MITERS - 3) % 3];
        float av[4], d1v[4];
        float s12 = 0.f, s22 = 0.f;
        #pragma unroll
        for (int k = 0; k < 4; ++k) {
            const int e = t + 256 * k;
            av[k] = zM[e];
            float bb = zM1[e], cc = zM2[e];
            d1v[k] = av[k] - bb;
            float d2 = bb - cc;
            s12 += d1v[k] * d2;
            s22 += d2 * d2;
        }
        #pragma unroll
        for (int off = 32; off >= 1; off >>= 1) s12 += __shfl_down(s12, off, 64);
        if (lane == 0) red4[wave] = s12;
        __syncthreads();
        if (t == 0) bvalS = red4[0] + red4[1] + red4[2] + red4[3];
        __syncthreads();
        const float dot12 = bvalS;
        __syncthreads();
        #pragma unroll
        for (int off = 32; off >= 1; off >>= 1) s22 += __shfl_down(s22, off, 64);
        if (lane == 0) red4[wave] = s22;
        __syncthreads();
        if (t == 0) bvalS = red4[0] + red4[1] + red4[2] + red4[3];
        __syncthreads();
        const float dot22 = bvalS;
        __syncthreads();

        float lam = dot12 / fmaxf(dot22, 1e-30f);
        lam = fminf(fmaxf(lam, 0.0f), 0.95f);
        const float coef = lam / (1.0f - lam);
        #pragma unroll
        for (int k = 0; k < 4; ++k) ush[t + 256 * k] = av[k] + coef * d1v[k];
        __syncthreads();

        float Pv[4];
        float ps = 0.f;
        #pragma unroll
        for (int k = 0; k < 4; ++k) {
            const int e = t + 256 * k;
            Pv[k] = (e >= 1) ? 0.1f * ush[e] : 0.f;
            ps += Pv[k];
        }
        #pragma unroll
        for (int off = 32; off >= 1; off >>= 1) ps += __shfl_down(ps, off, 64);
        if (lane == 0) red4[wave] = ps;
        __syncthreads();
        if (t == 0) bvalS = (red4[0] + red4[1] + red4[2] + red4[3]) / 1023.0f;
        __syncthreads();
        const float mean = bvalS;
        __syncthreads();

        float mx = 0.f;   // relu'd values >= 0
        #pragma unroll
        for (int k = 0; k < 4; ++k) {
            const int e = t + 256 * k;
            if (e >= 1) {
                Pv[k] = fmaxf(Pv[k] - mean, 0.f) * 100.f;
                mx = fmaxf(mx, Pv[k]);
            }
        }
        #pragma unroll
        for (int off = 32; off >= 1; off >>= 1) mx = fmaxf(mx, __shfl_down(mx, off, 64));
        if (lane == 0) red4[wave] = mx;
        __syncthreads();
        if (t == 0) bvalS = fmaxf(fmaxf(red4[0], red4[1]), fmaxf(red4[2], red4[3]));
        __syncthreads();
        const float gmax = bvalS;
        __syncthreads();

        float Ev[4];
        float es = 0.f;
        #pragma unroll
        for (int k = 0; k < 4; ++k) {
            const int e = t + 256 * k;
            Ev[k] = (e >= 1) ? expf(Pv[k] - gmax) : 0.f;
            es += Ev[k];
        }
        #pragma unroll
        for (int off = 32; off >= 1; off >>= 1) es += __shfl_down(es, off, 64);
        if (lane == 0) red4[wave] = es;
        __syncthreads();
        if (t == 0) bvalS = red4[0] + red4[1] + red4[2] + red4[3];
        __syncthreads();
        const float esum = bvalS;
        #pragma unroll
        for (int k = 0; k < 4; ++k) {
            const int e = t + 256 * k;
            if (e >= 1) out[e - 1] = Ev[k] / esum;
        }
    }
}

extern "C" void kernel_launch(void* const* d_in, const int* in_sizes, int n_in,
                              void* d_out, int out_size, void* d_ws, size_t ws_size,
                              hipStream_t stream) {
    const float* f  = (const float*)d_in[0];
    const float* w1 = (const float*)d_in[1];
    const float* b1 = (const float*)d_in[2];
    const float* w2 = (const float*)d_in[3];
    const float* b2 = (const float*)d_in[4];
    const float* w3 = (const float*)d_in[5];
    const float* b3 = (const float*)d_in[6];
    const float* w4 = (const float*)d_in[7];
    const float* b4 = (const float*)d_in[8];
    float* ws = (float*)d_ws;

    // float-unit offsets
    unsigned int* bars = (unsigned int*)ws;                 // 64 counters
    float* total = ws + 64;                                 // 1024
    float* fn2   = ws + 1088;                               // 1024
    float* mag   = ws + 2112;                               // 1024
    float* S     = ws + 3136;                               // 16384
    float* R     = ws + 19520;                              // 16384
    float* t1v   = ws + 35904;                              // 128
    float* t2v   = ws + 36032;                              // 128
    float* bboth = ws + 36160;                              // 256
    float* A0    = ws + 36416;                              // 1024
    float* zb0   = ws + 37440;                               // 1024
    float* zb1   = ws + 38464;                               // 1024
    float* zb2   = ws + 39488;                               // 1024
    unsigned short* xb = (unsigned short*)(ws + 40512);     // 65536 floats
    unsigned short* Bu = (unsigned short*)(ws + 106048);    // 524288 floats
    float* out = (float*)d_out;

    // zero barrier counters + total/fn2/mag in one memset (graph-capture safe)
    hipMemsetAsync(ws, 0, (64 + 3 * 1024) * sizeof(float), stream);

    k_mega<<<NB, 256, 0, stream>>>(f, w1, b1, w2, b2, w3, b3, w4, b4,
                                   bars, total, fn2, mag,
                                   S, R, t1v, t2v, bboth, A0,
                                   zb0, zb1, zb2, xb, Bu, out);
}

// Round 11
// 122.115 us; speedup vs baseline: 3.6205x; 3.2889x over previous
//
#include <hip/hip_runtime.h>
#include <math.h>

#define N 1024
#define NM1 1023
#define DIM 128
#define LAMB 0.9f
#define INV2SIG2 (1.0f / 450.0f)   // 0.5 / sigma^2, sigma=15
#define MITERS 6                   // Aitken chain; |lam2/lam1| ~ 4e-3 => M=6 has
                                   // ~8 orders of output-error margin (M=14 gave 0.0)

typedef short v8s __attribute__((ext_vector_type(8)));
typedef float v4f __attribute__((ext_vector_type(4)));

__device__ __forceinline__ unsigned short f2bf(float x) {   // RNE float->bf16
    unsigned int u = __float_as_uint(x);
    u += 0x7FFFu + ((u >> 16) & 1u);
    return (unsigned short)(u >> 16);
}
__device__ __forceinline__ float bf2f(unsigned short h) {
    return __uint_as_float(((unsigned int)h) << 16);
}

// ---------------- compose A: S=W3*W2 | R=W1*W4 | t1=W3 b2+b3, t2=W1 b4 | zero-init ---
__global__ __launch_bounds__(256) void k_compose_a(
    const float* __restrict__ w1, const float* __restrict__ w3,
    const float* __restrict__ w2, const float* __restrict__ w4,
    const float* __restrict__ b2, const float* __restrict__ b3,
    const float* __restrict__ b4,
    float* __restrict__ S, float* __restrict__ R,
    float* __restrict__ t1v, float* __restrict__ t2v,
    float* __restrict__ zeros)   // fn2/mag contiguous, 2048 floats
{
    const int b = blockIdx.x;
    const int t = threadIdx.x;
    if (b < 64) {                       // S[i][j] = sum_k W3[i,k] W2[k,j]
        const int i = 2 * b + (t >> 7), j = t & 127;
        float acc = 0.f;
        #pragma unroll 8
        for (int k = 0; k < 128; ++k) acc += w3[i * 128 + k] * w2[k * 128 + j];
        S[i * 128 + j] = acc;
    } else if (b < 128) {               // R[i][j] = sum_k W1[i,k] W4[k,j]
        const int i = 2 * (b - 64) + (t >> 7), j = t & 127;
        float acc = 0.f;
        #pragma unroll 8
        for (int k = 0; k < 128; ++k) acc += w1[i * 128 + k] * w4[k * 128 + j];
        R[i * 128 + j] = acc;
    } else if (b == 128) {
        if (t < 128) {                  // t1 = W3 b2 + b3
            float acc = b3[t];
            #pragma unroll 8
            for (int k = 0; k < 128; ++k) acc += w3[t * 128 + k] * b2[k];
            t1v[t] = acc;
        } else {                        // t2 = W1 b4
            const int i = t - 128;
            float acc = 0.f;
            #pragma unroll 8
            for (int k = 0; k < 128; ++k) acc += w1[i * 128 + k] * b4[k];
            t2v[i] = acc;
        }
    } else {                            // zero fn2/mag
        #pragma unroll
        for (int s = 0; s < 8; ++s) zeros[t + 256 * s] = 0.f;
    }
}

// ---------------- compose B: G=W4*S | X=R*S | bg=W4 t1+b4, bx=R t1+t2+b1 ------------
__global__ __launch_bounds__(256) void k_compose_b(
    const float* __restrict__ w4, const float* __restrict__ S,
    const float* __restrict__ R,
    const float* __restrict__ t1v, const float* __restrict__ t2v,
    const float* __restrict__ b1, const float* __restrict__ b4,
    float* __restrict__ Wboth, float* __restrict__ bboth)
{
    const int b = blockIdx.x;
    const int t = threadIdx.x;
    if (b < 64) {                       // G rows 0-127 of Wboth
        const int i = 2 * b + (t >> 7), j = t & 127;
        float acc = 0.f;
        #pragma unroll 8
        for (int k = 0; k < 128; ++k) acc += w4[i * 128 + k] * S[k * 128 + j];
        Wboth[i * 128 + j] = acc;
    } else if (b < 128) {               // X rows 128-255 of Wboth
        const int i = 2 * (b - 64) + (t >> 7), j = t & 127;
        float acc = 0.f;
        #pragma unroll 8
        for (int k = 0; k < 128; ++k) acc += R[i * 128 + k] * S[k * 128 + j];
        Wboth[(128 + i) * 128 + j] = acc;
    } else {
        if (t < 128) {                  // bg = W4 t1 + b4
            float acc = b4[t];
            #pragma unroll 8
            for (int k = 0; k < 128; ++k) acc += w4[t * 128 + k] * t1v[k];
            bboth[t] = acc;
        } else {                        // bx = R t1 + t2 + b1
            const int i = t - 128;
            float acc = t2v[i] + b1[i];
            #pragma unroll 8
            for (int k = 0; k < 128; ++k) acc += R[i * 128 + k] * t1v[k];
            bboth[128 + i] = acc;
        }
    }
}

// ---------------- K1: Y = f @ Wboth^T + bboth; xb (bf16) + fn2/mag ----------
__global__ __launch_bounds__(256) void k_gemm(
    const float* __restrict__ f, const float* __restrict__ Wb,
    const float* __restrict__ bb,
    unsigned short* __restrict__ xb, float* __restrict__ fn2, float* __restrict__ mag)
{
    __shared__ float4 fl4[64][33];
    __shared__ float4 wl4[64][33];
    __shared__ float bsh[64];
    const int t = threadIdx.x;
    const int row0 = blockIdx.y * 64;
    const int col0 = blockIdx.x * 64;   // over 256 outputs
    const float4* F4 = (const float4*)f;
    const float4* W4p = (const float4*)Wb;

    #pragma unroll
    for (int s = 0; s < 8; ++s) {
        int idx = t + 256 * s;
        int r = idx >> 5, k4 = idx & 31;
        fl4[r][k4] = F4[(row0 + r) * 32 + k4];
        wl4[r][k4] = W4p[(col0 + r) * 32 + k4];
    }
    if (t < 64) bsh[t] = bb[col0 + t];
    __syncthreads();

    const int tx = t & 15, ty = t >> 4;
    float acc[4][4];
    #pragma unroll
    for (int i = 0; i < 4; ++i)
        #pragma unroll
        for (int j = 0; j < 4; ++j) acc[i][j] = 0.f;

    for (int k4 = 0; k4 < 32; ++k4) {
        float4 fa[4], wv[4];
        #pragma unroll
        for (int i = 0; i < 4; ++i) fa[i] = fl4[ty + 16 * i][k4];
        #pragma unroll
        for (int j = 0; j < 4; ++j) wv[j] = wl4[tx + 16 * j][k4];
        #pragma unroll
        for (int i = 0; i < 4; ++i)
            #pragma unroll
            for (int j = 0; j < 4; ++j)
                acc[i][j] += fa[i].x * wv[j].x + fa[i].y * wv[j].y
                           + fa[i].z * wv[j].z + fa[i].w * wv[j].w;
    }

    const bool isg = (col0 < 128);
    #pragma unroll
    for (int i = 0; i < 4; ++i) {
        int gr = row0 + ty + 16 * i;
        float ss = 0.f;
        #pragma unroll
        for (int j = 0; j < 4; ++j) {
            int c = tx + 16 * j;
            float yv = acc[i][j] + bsh[c];
            ss += yv * yv;
            if (!isg) xb[gr * DIM + (col0 - 128) + c] = f2bf(yv);
        }
        #pragma unroll
        for (int off = 1; off < 16; off <<= 1) ss += __shfl_xor(ss, off, 64);
        if (tx == 0) atomicAdd(isg ? &fn2[gr] : &mag[gr], ss);
    }
}

// ---------------- K2: fused affinity + normalize + P0: row-slab, no atomics ---------
__global__ __launch_bounds__(512) void k_affB(
    const unsigned short* __restrict__ xb, const float* __restrict__ mag,
    const float* __restrict__ fn2,
    unsigned short* __restrict__ Bb, float* __restrict__ P0f)
{
    __shared__ float strip[16][1028];
    __shared__ float part[8][16];
    __shared__ float rtot[16];
    const int t = threadIdx.x;
    const int wave = t >> 6, lane = t & 63;
    const int l15 = lane & 15, quad = lane >> 4;
    const int i0 = blockIdx.x * 16;

    const unsigned short* ap = xb + (i0 + l15) * DIM + quad * 8;
    v8s afr[4];
    #pragma unroll
    for (int kc = 0; kc < 4; ++kc) afr[kc] = *(const v8s*)(ap + kc * 32);

    float rowsum[4] = {0.f, 0.f, 0.f, 0.f};
    for (int s = 0; s < 8; ++s) {
        const int j0 = (wave * 8 + s) * 16;
        const unsigned short* bp = xb + (j0 + l15) * DIM + quad * 8;
        v4f acc = {0.f, 0.f, 0.f, 0.f};
        #pragma unroll
        for (int kc = 0; kc < 4; ++kc) {
            v8s b = *(const v8s*)(bp + kc * 32);
            acc = __builtin_amdgcn_mfma_f32_16x16x32_bf16(afr[kc], b, acc, 0, 0, 0);
        }
        const int gj = j0 + l15;
        const float rm = 1.0f / mag[gj];
        const float fj = fn2[gj] * INV2SIG2;
        #pragma unroll
        for (int reg = 0; reg < 4; ++reg) {
            int row = quad * 4 + reg;
            float Sv = acc[reg] * rm - 1.0f;
            float a = ((i0 + row) == gj) ? 0.f : __expf(-(Sv * Sv) * fj);
            strip[row][gj] = a;
            rowsum[reg] += a;
        }
    }
    #pragma unroll
    for (int reg = 0; reg < 4; ++reg) {
        float v = rowsum[reg];
        #pragma unroll
        for (int off = 1; off < 16; off <<= 1) v += __shfl_xor(v, off, 64);
        if (l15 == 0) part[wave][quad * 4 + reg] = v;
    }
    __syncthreads();
    if (t < 16) {
        float s = 0.f;
        #pragma unroll
        for (int w = 0; w < 8; ++w) s += part[w][t];
        rtot[t] = s;
    }
    __syncthreads();

    if (i0 == 0) {
        float r0 = 1.0f / fmaxf(rtot[0], 1e-10f);
        for (int j = t; j < N; j += 512)
            P0f[j] = (j == 0) ? 0.f : strip[0][j] * r0;
    }

    // Bb rows: 2048 8-elem packs, 4 per thread
    #pragma unroll
    for (int it = 0; it < 4; ++it) {
        int pidx = t + 512 * it;
        int row = pidx >> 7;
        int c8 = (pidx & 127) * 8;
        int gi = i0 + row;
        float sc = (gi == 0) ? 0.f : LAMB / fmaxf(rtot[row], 1e-10f);
        float4 v0 = *(const float4*)&strip[row][c8];
        float4 v1 = *(const float4*)&strip[row][c8 + 4];
        uint4 p;
        unsigned short* pp = (unsigned short*)&p;
        pp[0] = f2bf((c8 == 0) ? 0.f : v0.x * sc);
        pp[1] = f2bf(v0.y * sc); pp[2] = f2bf(v0.z * sc); pp[3] = f2bf(v0.w * sc);
        pp[4] = f2bf(v1.x * sc); pp[5] = f2bf(v1.y * sc);
        pp[6] = f2bf(v1.z * sc); pp[7] = f2bf(v1.w * sc);
        *(uint4*)(Bb + gi * N + c8) = p;
    }
}

// ---------------- K5: v[r] = base[r] + (M z)[r], bf16 matrix ----------
__global__ __launch_bounds__(256) void k_mvb(
    const unsigned short* __restrict__ M, const float* __restrict__ base,
    const float* __restrict__ z, float* __restrict__ v)
{
    const int r = (blockIdx.x * 256 + threadIdx.x) >> 6;
    const int lane = threadIdx.x & 63;
    const uint4* m4 = (const uint4*)(M + r * N + lane * 16);
    const float4* z4 = (const float4*)(z + lane * 16);
    uint4 ma = m4[0], mb = m4[1];
    float4 z0 = z4[0], z1 = z4[1], z2 = z4[2], z3 = z4[3];
    float acc = 0.f;
    acc += bf2f((unsigned short)(ma.x)) * z0.x + bf2f((unsigned short)(ma.x >> 16)) * z0.y;
    acc += bf2f((unsigned short)(ma.y)) * z0.z + bf2f((unsigned short)(ma.y >> 16)) * z0.w;
    acc += bf2f((unsigned short)(ma.z)) * z1.x + bf2f((unsigned short)(ma.z >> 16)) * z1.y;
    acc += bf2f((unsigned short)(ma.w)) * z1.z + bf2f((unsigned short)(ma.w >> 16)) * z1.w;
    acc += bf2f((unsigned short)(mb.x)) * z2.x + bf2f((unsigned short)(mb.x >> 16)) * z2.y;
    acc += bf2f((unsigned short)(mb.y)) * z2.z + bf2f((unsigned short)(mb.y >> 16)) * z2.w;
    acc += bf2f((unsigned short)(mb.z)) * z3.x + bf2f((unsigned short)(mb.z >> 16)) * z3.y;
    acc += bf2f((unsigned short)(mb.w)) * z3.z + bf2f((unsigned short)(mb.w >> 16)) * z3.w;
    #pragma unroll
    for (int off = 32; off >= 1; off >>= 1) acc += __shfl_xor(acc, off, 64);
    if (lane == 0) v[r] = base[r] + acc;
}

// ---------------- K6: Aitken extrapolation + epilogue (one block) ----------
__global__ __launch_bounds__(1024) void k_epilogue(
    const float* __restrict__ zM, const float* __restrict__ zM1,
    const float* __restrict__ zM2, float* __restrict__ out)
{
    __shared__ float red[16];
    __shared__ float bval;
    __shared__ float ush[1024];
    const int t = threadIdx.x;
    const int wv = t >> 6, lane = t & 63;

    const float a  = zM[t];
    const float b  = zM1[t];
    const float c  = zM2[t];
    const float d1 = a - b;
    const float d2 = b - c;

    // dot(d1,d2)
    float s = d1 * d2;
    #pragma unroll
    for (int off = 32; off >= 1; off >>= 1) s += __shfl_down(s, off, 64);
    if (lane == 0) red[wv] = s;
    __syncthreads();
    if (t < 64) {
        float s2 = (t < 16) ? red[t] : 0.f;
        #pragma unroll
        for (int off = 8; off >= 1; off >>= 1) s2 += __shfl_down(s2, off, 64);
        if (t == 0) bval = s2;
    }
    __syncthreads();
    const float dot12 = bval;
    __syncthreads();

    // dot(d2,d2)
    s = d2 * d2;
    #pragma unroll
    for (int off = 32; off >= 1; off >>= 1) s += __shfl_down(s, off, 64);
    if (lane == 0) red[wv] = s;
    __syncthreads();
    if (t < 64) {
        float s2 = (t < 16) ? red[t] : 0.f;
        #pragma unroll
        for (int off = 8; off >= 1; off >>= 1) s2 += __shfl_down(s2, off, 64);
        if (t == 0) bval = s2;
    }
    __syncthreads();
    const float dot22 = bval;
    __syncthreads();

    float lam = dot12 / fmaxf(dot22, 1e-30f);
    lam = fminf(fmaxf(lam, 0.0f), 0.95f);
    ush[t] = a + (lam / (1.0f - lam)) * d1;   // u_ext[t]
    __syncthreads();

    const bool valid = t < NM1;
    float P = valid ? 0.1f * ush[t + 1] : 0.f;

    // mean
    s = P;
    #pragma unroll
    for (int off = 32; off >= 1; off >>= 1) s += __shfl_down(s, off, 64);
    if (lane == 0) red[wv] = s;
    __syncthreads();
    if (t < 64) {
        float s2 = (t < 16) ? red[t] : 0.f;
        #pragma unroll
        for (int off = 8; off >= 1; off >>= 1) s2 += __shfl_down(s2, off, 64);
        if (t == 0) bval = s2 / 1023.0f;
    }
    __syncthreads();
    const float mean = bval;
    P = valid ? fmaxf(P - mean, 0.f) * 100.f : 0.f;

    // max
    __syncthreads();
    float m = P;
    #pragma unroll
    for (int off = 32; off >= 1; off >>= 1) m = fmaxf(m, __shfl_down(m, off, 64));
    if (lane == 0) red[wv] = m;
    __syncthreads();
    if (t < 64) {
        float m2 = (t < 16) ? red[t] : 0.f;
        #pragma unroll
        for (int off = 8; off >= 1; off >>= 1) m2 = fmaxf(m2, __shfl_down(m2, off, 64));
        if (t == 0) bval = m2;
    }
    __syncthreads();
    const float gmax = bval;
    const float e = valid ? expf(P - gmax) : 0.f;

    // sum
    __syncthreads();
    s = e;
    #pragma unroll
    for (int off = 32; off >= 1; off >>= 1) s += __shfl_down(s, off, 64);
    if (lane == 0) red[wv] = s;
    __syncthreads();
    if (t < 64) {
        float s2 = (t < 16) ? red[t] : 0.f;
        #pragma unroll
        for (int off = 8; off >= 1; off >>= 1) s2 += __shfl_down(s2, off, 64);
        if (t == 0) bval = s2;
    }
    __syncthreads();
    if (valid) out[t] = e / bval;
}

extern "C" void kernel_launch(void* const* d_in, const int* in_sizes, int n_in,
                              void* d_out, int out_size, void* d_ws, size_t ws_size,
                              hipStream_t stream) {
    const float* f  = (const float*)d_in[0];
    const float* w1 = (const float*)d_in[1];
    const float* b1 = (const float*)d_in[2];
    const float* w2 = (const float*)d_in[3];
    const float* b2 = (const float*)d_in[4];
    const float* w3 = (const float*)d_in[5];
    const float* b3 = (const float*)d_in[6];
    const float* w4 = (const float*)d_in[7];
    const float* b4 = (const float*)d_in[8];
    float* ws = (float*)d_ws;

    // Offsets in FLOAT units. bf16 1024x1024 matrix = 524288 floats of space.
    float* S     = ws;                  // 16384
    float* R     = ws + 16384;          // 16384
    float* Wboth = ws + 32768;          // 32768
    float* bboth = ws + 65536;          // 256
    float* t1v   = ws + 65792;          // 128
    float* t2v   = ws + 65920;          // 128
    float* fn2   = ws + 66048;          // 1024 (fn2/mag contiguous for zero-init)
    float* mag   = ws + 67072;          // 1024
    float* P0f   = ws + 68096;          // 1024
    float* tb0   = ws + 69120;          // 1024
    float* tb1   = ws + 70144;          // 1024
    float* tb2   = ws + 71168;          // 1024
    unsigned short* xb = (unsigned short*)(ws + 72192);   // 65536 floats
    unsigned short* Bb = (unsigned short*)(ws + 137728);  // 524288 floats
    float* out = (float*)d_out;

    k_compose_a<<<130, 256, 0, stream>>>(w1, w3, w2, w4, b2, b3, b4,
                                         S, R, t1v, t2v, fn2);
    k_compose_b<<<129, 256, 0, stream>>>(w4, S, R, t1v, t2v, b1, b4, Wboth, bboth);

    k_gemm<<<dim3(4, 16), 256, 0, stream>>>(f, Wboth, bboth, xb, fn2, mag);
    k_affB<<<64, 512, 0, stream>>>(xb, mag, fn2, Bb, P0f);

    // Neumann chain z <- P0 + B z, MITERS steps, 3-buffer rotation
    float* zb[3] = {tb0, tb1, tb2};
    float* zin = P0f;
    for (int it = 0; it < MITERS; ++it) {
        float* zout = zb[it % 3];
        k_mvb<<<256, 256, 0, stream>>>(Bb, P0f, zin, zout);
        zin = zout;
    }
    k_epilogue<<<1, 1024, 0, stream>>>(zb[(MITERS - 1) % 3],
                                       zb[(MITERS - 2) % 3],
                                       zb[(MITERS - 3) % 3], out);
}

// Round 12
// 109.158 us; speedup vs baseline: 4.0503x; 1.1187x over previous
//
#include <hip/hip_runtime.h>
#include <math.h>

#define N 1024
#define NM1 1023
#define DIM 128
#define LAMB 0.9f
#define INV2SIG2 (1.0f / 450.0f)   // 0.5 / sigma^2, sigma=15
#define MITERS 4                   // Aitken chain; rank-one-dominated B => huge margin

typedef short v8s __attribute__((ext_vector_type(8)));
typedef float v4f __attribute__((ext_vector_type(4)));

__device__ __forceinline__ unsigned short f2bf(float x) {   // RNE float->bf16
    unsigned int u = __float_as_uint(x);
    u += 0x7FFFu + ((u >> 16) & 1u);
    return (unsigned short)(u >> 16);
}
__device__ __forceinline__ float bf2f(unsigned short h) {
    return __uint_as_float(((unsigned int)h) << 16);
}
__device__ __forceinline__ v8s cvt8(const float* p) {      // 8 fp32 -> v8s bf16
    v8s r;
    #pragma unroll
    for (int i = 0; i < 8; ++i) r[i] = (short)f2bf(p[i]);
    return r;
}

// ---------------- compose A: S=W3*W2 | R=W1*W4 | t1=W3 b2+b3, t2=W1 b4 | zero-init ---
__global__ __launch_bounds__(256) void k_compose_a(
    const float* __restrict__ w1, const float* __restrict__ w3,
    const float* __restrict__ w2, const float* __restrict__ w4,
    const float* __restrict__ b2, const float* __restrict__ b3,
    const float* __restrict__ b4,
    float* __restrict__ S, float* __restrict__ R,
    float* __restrict__ t1v, float* __restrict__ t2v,
    float* __restrict__ zeros)   // fn2/mag/total contiguous, 3072 floats
{
    const int b = blockIdx.x;
    const int t = threadIdx.x;
    if (b < 64) {                       // S[i][j] = sum_k W3[i,k] W2[k,j]
        const int i = 2 * b + (t >> 7), j = t & 127;
        float acc = 0.f;
        #pragma unroll 8
        for (int k = 0; k < 128; ++k) acc += w3[i * 128 + k] * w2[k * 128 + j];
        S[i * 128 + j] = acc;
    } else if (b < 128) {               // R[i][j] = sum_k W1[i,k] W4[k,j]
        const int i = 2 * (b - 64) + (t >> 7), j = t & 127;
        float acc = 0.f;
        #pragma unroll 8
        for (int k = 0; k < 128; ++k) acc += w1[i * 128 + k] * w4[k * 128 + j];
        R[i * 128 + j] = acc;
    } else if (b == 128) {
        if (t < 128) {                  // t1 = W3 b2 + b3
            float acc = b3[t];
            #pragma unroll 8
            for (int k = 0; k < 128; ++k) acc += w3[t * 128 + k] * b2[k];
            t1v[t] = acc;
        } else {                        // t2 = W1 b4
            const int i = t - 128;
            float acc = 0.f;
            #pragma unroll 8
            for (int k = 0; k < 128; ++k) acc += w1[i * 128 + k] * b4[k];
            t2v[i] = acc;
        }
    } else {                            // zero fn2/mag/total (3072 floats)
        #pragma unroll
        for (int s = 0; s < 12; ++s) zeros[t + 256 * s] = 0.f;
    }
}

// ---------------- compose B: G=W4*S | X=R*S | bg=W4 t1+b4, bx=R t1+t2+b1 ------------
__global__ __launch_bounds__(256) void k_compose_b(
    const float* __restrict__ w4, const float* __restrict__ S,
    const float* __restrict__ R,
    const float* __restrict__ t1v, const float* __restrict__ t2v,
    const float* __restrict__ b1, const float* __restrict__ b4,
    float* __restrict__ Wboth, float* __restrict__ bboth)
{
    const int b = blockIdx.x;
    const int t = threadIdx.x;
    if (b < 64) {                       // G rows 0-127 of Wboth
        const int i = 2 * b + (t >> 7), j = t & 127;
        float acc = 0.f;
        #pragma unroll 8
        for (int k = 0; k < 128; ++k) acc += w4[i * 128 + k] * S[k * 128 + j];
        Wboth[i * 128 + j] = acc;
    } else if (b < 128) {               // X rows 128-255 of Wboth
        const int i = 2 * (b - 64) + (t >> 7), j = t & 127;
        float acc = 0.f;
        #pragma unroll 8
        for (int k = 0; k < 128; ++k) acc += R[i * 128 + k] * S[k * 128 + j];
        Wboth[(128 + i) * 128 + j] = acc;
    } else {
        if (t < 128) {                  // bg = W4 t1 + b4
            float acc = b4[t];
            #pragma unroll 8
            for (int k = 0; k < 128; ++k) acc += w4[t * 128 + k] * t1v[k];
            bboth[t] = acc;
        } else {                        // bx = R t1 + t2 + b1
            const int i = t - 128;
            float acc = t2v[i] + b1[i];
            #pragma unroll 8
            for (int k = 0; k < 128; ++k) acc += R[i * 128 + k] * t1v[k];
            bboth[128 + i] = acc;
        }
    }
}

// ---------------- K1: 256-block MFMA gemm Y = f @ Wb^T + bboth; xb, fn2, mag --------
// (mega phase-2 pattern, verified rounds 9/10)
__global__ __launch_bounds__(256) void k_gemm2(
    const float* __restrict__ f, const float* __restrict__ Wb,
    const float* __restrict__ bb,
    unsigned short* __restrict__ xb, float* __restrict__ fn2, float* __restrict__ mag)
{
    const int b = blockIdx.x, t = threadIdx.x;
    const int wave = t >> 6, lane = t & 63;
    const int l15 = lane & 15, quad = lane >> 4;
    const int i0 = (b >> 4) * 64;       // 16 row-tiles of 64
    const int j0 = (b & 15) * 16;       // 16 col-tiles of 16 (over 256 outputs)
    const int ri = i0 + wave * 16;
    const float* ap = f  + (ri + l15) * 128 + quad * 8;
    const float* bp = Wb + (j0 + l15) * 128 + quad * 8;
    v4f acc = {0.f, 0.f, 0.f, 0.f};
    #pragma unroll
    for (int kc = 0; kc < 4; ++kc) {
        v8s a  = cvt8(ap + kc * 32);
        v8s bbv = cvt8(bp + kc * 32);
        acc = __builtin_amdgcn_mfma_f32_16x16x32_bf16(a, bbv, acc, 0, 0, 0);
    }
    const float bias = bb[j0 + l15];
    const bool isx = (j0 >= 128);
    float sq[4];
    #pragma unroll
    for (int reg = 0; reg < 4; ++reg) {
        float yv = acc[reg] + bias;
        sq[reg] = yv * yv;
        if (isx) xb[(ri + quad * 4 + reg) * DIM + (j0 - 128) + l15] = f2bf(yv);
    }
    #pragma unroll
    for (int reg = 0; reg < 4; ++reg) {
        float ss = sq[reg];
        ss += __shfl_xor(ss, 1, 64); ss += __shfl_xor(ss, 2, 64);
        ss += __shfl_xor(ss, 4, 64); ss += __shfl_xor(ss, 8, 64);
        if (l15 == 0)
            atomicAdd((isx ? mag : fn2) + (ri + quad * 4 + reg), ss);
    }
}

// ---------------- K2: 256-block affinity -> Bu (UNSCALED bf16), totals, A0 ----------
// (mega phase-3 pattern, verified; scale lambda/total_r folds into k_mvb2)
__global__ __launch_bounds__(256) void k_aff(
    const unsigned short* __restrict__ xb, const float* __restrict__ mag,
    const float* __restrict__ fn2,
    unsigned short* __restrict__ Bu, float* __restrict__ A0,
    float* __restrict__ total)
{
    const int b = blockIdx.x, t = threadIdx.x;
    const int wave = t >> 6, lane = t & 63;
    const int l15 = lane & 15, quad = lane >> 4;
    const int slab = b >> 2;            // rows slab*16..+16
    const int qtr  = b & 3;             // j-quarter (256 cols)
    const int i0 = slab * 16;

    const unsigned short* ap = xb + (i0 + l15) * DIM + quad * 8;
    v8s afr[4];
    #pragma unroll
    for (int kc = 0; kc < 4; ++kc) afr[kc] = *(const v8s*)(ap + kc * 32);

    float rowsum[4] = {0.f, 0.f, 0.f, 0.f};
    #pragma unroll
    for (int s = 0; s < 4; ++s) {
        const int j0 = (qtr * 16 + wave * 4 + s) * 16;
        const unsigned short* bp = xb + (j0 + l15) * DIM + quad * 8;
        v4f acc = {0.f, 0.f, 0.f, 0.f};
        #pragma unroll
        for (int kc = 0; kc < 4; ++kc)
            acc = __builtin_amdgcn_mfma_f32_16x16x32_bf16(
                      afr[kc], *(const v8s*)(bp + kc * 32), acc, 0, 0, 0);
        const int gj = j0 + l15;
        const float rm = 1.0f / mag[gj];
        const float fj = fn2[gj] * INV2SIG2;
        #pragma unroll
        for (int reg = 0; reg < 4; ++reg) {
            const int gi = i0 + quad * 4 + reg;
            float Sv = acc[reg] * rm - 1.0f;
            float a = (gi == gj) ? 0.f : __expf(-(Sv * Sv) * fj);
            Bu[gi * N + gj] = f2bf(a);
            rowsum[reg] += a;
            if (gi == 0) A0[gj] = a;    // fp32 row 0 for P0
        }
    }
    #pragma unroll
    for (int reg = 0; reg < 4; ++reg) {
        float ss = rowsum[reg];
        ss += __shfl_xor(ss, 1, 64); ss += __shfl_xor(ss, 2, 64);
        ss += __shfl_xor(ss, 4, 64); ss += __shfl_xor(ss, 8, 64);
        if (l15 == 0) atomicAdd(&total[i0 + quad * 4 + reg], ss);
    }
}

// ---------------- K5: v[r] = P0[r] + rscale * (Bu z)[r]; scale folded (round 10) ----
// first=1: z is A0 (fp32 unscaled row0), zscale = 1/total0 applied after the dot.
__global__ __launch_bounds__(256) void k_mvb2(
    const unsigned short* __restrict__ M, const float* __restrict__ A0,
    const float* __restrict__ total,
    const float* __restrict__ z, float* __restrict__ v, int first)
{
    const int r = (blockIdx.x * 256 + threadIdx.x) >> 6;
    const int lane = threadIdx.x & 63;
    const float r0s = 1.0f / fmaxf(total[0], 1e-10f);
    const float rscale = (r == 0) ? 0.f : LAMB / fmaxf(total[r], 1e-10f);
    const float p0r    = (r == 0) ? 0.f : A0[r] * r0s;
    const float zscale = first ? r0s : 1.0f;

    const uint4* m4 = (const uint4*)(M + r * N + lane * 16);
    const float4* z4 = (const float4*)(z + lane * 16);
    uint4 ma = m4[0], mb = m4[1];
    float4 z0 = z4[0], z1 = z4[1], z2 = z4[2], z3 = z4[3];
    float acc = 0.f;
    acc += bf2f((unsigned short)(ma.x)) * z0.x + bf2f((unsigned short)(ma.x >> 16)) * z0.y;
    acc += bf2f((unsigned short)(ma.y)) * z0.z + bf2f((unsigned short)(ma.y >> 16)) * z0.w;
    acc += bf2f((unsigned short)(ma.z)) * z1.x + bf2f((unsigned short)(ma.z >> 16)) * z1.y;
    acc += bf2f((unsigned short)(ma.w)) * z1.z + bf2f((unsigned short)(ma.w >> 16)) * z1.w;
    acc += bf2f((unsigned short)(mb.x)) * z2.x + bf2f((unsigned short)(mb.x >> 16)) * z2.y;
    acc += bf2f((unsigned short)(mb.y)) * z2.z + bf2f((unsigned short)(mb.y >> 16)) * z2.w;
    acc += bf2f((unsigned short)(mb.z)) * z3.x + bf2f((unsigned short)(mb.z >> 16)) * z3.y;
    acc += bf2f((unsigned short)(mb.w)) * z3.z + bf2f((unsigned short)(mb.w >> 16)) * z3.w;
    #pragma unroll
    for (int off = 32; off >= 1; off >>= 1) acc += __shfl_xor(acc, off, 64);
    if (lane == 0) v[r] = p0r + rscale * zscale * acc;
}

// ---------------- K6: Aitken extrapolation + epilogue (one block) ----------
__global__ __launch_bounds__(1024) void k_epilogue(
    const float* __restrict__ zM, const float* __restrict__ zM1,
    const float* __restrict__ zM2, float* __restrict__ out)
{
    __shared__ float red[16];
    __shared__ float bval;
    __shared__ float ush[1024];
    const int t = threadIdx.x;
    const int wv = t >> 6, lane = t & 63;

    const float a  = zM[t];
    const float b  = zM1[t];
    const float c  = zM2[t];
    const float d1 = a - b;
    const float d2 = b - c;

    // dot(d1,d2)
    float s = d1 * d2;
    #pragma unroll
    for (int off = 32; off >= 1; off >>= 1) s += __shfl_down(s, off, 64);
    if (lane == 0) red[wv] = s;
    __syncthreads();
    if (t < 64) {
        float s2 = (t < 16) ? red[t] : 0.f;
        #pragma unroll
        for (int off = 8; off >= 1; off >>= 1) s2 += __shfl_down(s2, off, 64);
        if (t == 0) bval = s2;
    }
    __syncthreads();
    const float dot12 = bval;
    __syncthreads();

    // dot(d2,d2)
    s = d2 * d2;
    #pragma unroll
    for (int off = 32; off >= 1; off >>= 1) s += __shfl_down(s, off, 64);
    if (lane == 0) red[wv] = s;
    __syncthreads();
    if (t < 64) {
        float s2 = (t < 16) ? red[t] : 0.f;
        #pragma unroll
        for (int off = 8; off >= 1; off >>= 1) s2 += __shfl_down(s2, off, 64);
        if (t == 0) bval = s2;
    }
    __syncthreads();
    const float dot22 = bval;
    __syncthreads();

    float lam = dot12 / fmaxf(dot22, 1e-30f);
    lam = fminf(fmaxf(lam, 0.0f), 0.95f);
    ush[t] = a + (lam / (1.0f - lam)) * d1;   // u_ext[t]
    __syncthreads();

    const bool valid = t < NM1;
    float P = valid ? 0.1f * ush[t + 1] : 0.f;

    // mean
    s = P;
    #pragma unroll
    for (int off = 32; off >= 1; off >>= 1) s += __shfl_down(s, off, 64);
    if (lane == 0) red[wv] = s;
    __syncthreads();
    if (t < 64) {
        float s2 = (t < 16) ? red[t] : 0.f;
        #pragma unroll
        for (int off = 8; off >= 1; off >>= 1) s2 += __shfl_down(s2, off, 64);
        if (t == 0) bval = s2 / 1023.0f;
    }
    __syncthreads();
    const float mean = bval;
    P = valid ? fmaxf(P - mean, 0.f) * 100.f : 0.f;

    // max
    __syncthreads();
    float m = P;
    #pragma unroll
    for (int off = 32; off >= 1; off >>= 1) m = fmaxf(m, __shfl_down(m, off, 64));
    if (lane == 0) red[wv] = m;
    __syncthreads();
    if (t < 64) {
        float m2 = (t < 16) ? red[t] : 0.f;
        #pragma unroll
        for (int off = 8; off >= 1; off >>= 1) m2 = fmaxf(m2, __shfl_down(m2, off, 64));
        if (t == 0) bval = m2;
    }
    __syncthreads();
    const float gmax = bval;
    const float e = valid ? expf(P - gmax) : 0.f;

    // sum
    __syncthreads();
    s = e;
    #pragma unroll
    for (int off = 32; off >= 1; off >>= 1) s += __shfl_down(s, off, 64);
    if (lane == 0) red[wv] = s;
    __syncthreads();
    if (t < 64) {
        float s2 = (t < 16) ? red[t] : 0.f;
        #pragma unroll
        for (int off = 8; off >= 1; off >>= 1) s2 += __shfl_down(s2, off, 64);
        if (t == 0) bval = s2;
    }
    __syncthreads();
    if (valid) out[t] = e / bval;
}

extern "C" void kernel_launch(void* const* d_in, const int* in_sizes, int n_in,
                              void* d_out, int out_size, void* d_ws, size_t ws_size,
                              hipStream_t stream) {
    const float* f  = (const float*)d_in[0];
    const float* w1 = (const float*)d_in[1];
    const float* b1 = (const float*)d_in[2];
    const float* w2 = (const float*)d_in[3];
    const float* b2 = (const float*)d_in[4];
    const float* w3 = (const float*)d_in[5];
    const float* b3 = (const float*)d_in[6];
    const float* w4 = (const float*)d_in[7];
    const float* b4 = (const float*)d_in[8];
    float* ws = (float*)d_ws;

    // Offsets in FLOAT units. bf16 1024x1024 matrix = 524288 floats of space.
    float* S     = ws;                  // 16384
    float* R     = ws + 16384;          // 16384
    float* Wboth = ws + 32768;          // 32768
    float* bboth = ws + 65536;          // 256
    float* t1v   = ws + 65792;          // 128
    float* t2v   = ws + 65920;          // 128
    float* fn2   = ws + 66048;          // 1024 (fn2/mag/total contiguous: zeroed)
    float* mag   = ws + 67072;          // 1024
    float* total = ws + 68096;          // 1024
    float* A0    = ws + 69120;          // 1024
    float* zb0   = ws + 70144;          // 1024
    float* zb1   = ws + 71168;          // 1024
    float* zb2   = ws + 72192;          // 1024
    unsigned short* xb = (unsigned short*)(ws + 73216);   // 65536 floats
    unsigned short* Bu = (unsigned short*)(ws + 138752);  // 524288 floats
    float* out = (float*)d_out;

    k_compose_a<<<130, 256, 0, stream>>>(w1, w3, w2, w4, b2, b3, b4,
                                         S, R, t1v, t2v, fn2);
    k_compose_b<<<129, 256, 0, stream>>>(w4, S, R, t1v, t2v, b1, b4, Wboth, bboth);

    k_gemm2<<<256, 256, 0, stream>>>(f, Wboth, bboth, xb, fn2, mag);
    k_aff<<<256, 256, 0, stream>>>(xb, mag, fn2, Bu, A0, total);

    // Neumann chain, MITERS steps; it 0 consumes fp32 A0 with folded 1/total0
    float* zb[3] = {zb0, zb1, zb2};
    const float* zin = A0;
    for (int it = 0; it < MITERS; ++it) {
        float* zout = zb[it % 3];
        k_mvb2<<<256, 256, 0, stream>>>(Bu, A0, total, zin, zout, it == 0 ? 1 : 0);
        zin = zout;
    }
    k_epilogue<<<1, 1024, 0, stream>>>(zb[(MITERS - 1) % 3],
                                       zb[(MITERS - 2) % 3],
                                       zb[(MITERS - 3) % 3], out);
}

// Round 14
// 108.579 us; speedup vs baseline: 4.0719x; 1.0053x over previous
//
#include <hip/hip_runtime.h>
#include <math.h>

#define N 1024
#define NM1 1023
#define DIM 128
#define LAMB 0.9f
#define INV2SIG2 (1.0f / 450.0f)   // 0.5 / sigma^2, sigma=15
#define MITERS 3                   // Aitken minimum; rank-one-dominated B

typedef short v8s __attribute__((ext_vector_type(8)));
typedef float v4f __attribute__((ext_vector_type(4)));

__device__ __forceinline__ unsigned short f2bf(float x) {   // RNE float->bf16
    unsigned int u = __float_as_uint(x);
    u += 0x7FFFu + ((u >> 16) & 1u);
    return (unsigned short)(u >> 16);
}
__device__ __forceinline__ float bf2f(unsigned short h) {
    return __uint_as_float(((unsigned int)h) << 16);
}
__device__ __forceinline__ v8s cvt8(const float* p) {      // 8 fp32 -> v8s bf16
    v8s r;
    #pragma unroll
    for (int i = 0; i < 8; ++i) r[i] = (short)f2bf(p[i]);
    return r;
}

// ---------------- K0: fused compose: Wboth rows = G|X via per-row chains; biases;
//                  zero fn2/mag/total/donecnt ----------
// G[i,:] = (W4[i,:]*W3)*W2 ; X[i,:] = ((W1[i,:]*W4)*W3)*W2
// beta3 = W3 b2 + b3 ; bg = W4 beta3 + b4 ; bx = W1 bg + b1
__global__ __launch_bounds__(256) void k_compose(
    const float* __restrict__ w1, const float* __restrict__ w2,
    const float* __restrict__ w3, const float* __restrict__ w4,
    const float* __restrict__ b1, const float* __restrict__ b2,
    const float* __restrict__ b3, const float* __restrict__ b4,
    float* __restrict__ Wboth, float* __restrict__ bboth,
    float* __restrict__ zeros)   // fn2/mag/total/donecnt contiguous, 3328 floats
{
    __shared__ float u0[2][128];
    __shared__ float u1[2][128];
    const int b = blockIdx.x, t = threadIdx.x;
    const int h = t >> 7, j = t & 127;
    if (b < 64) {                       // G rows 2b, 2b+1
        const int i = 2 * b + h;
        float acc = 0.f;
        #pragma unroll 8
        for (int k = 0; k < 128; ++k) acc += w4[i * 128 + k] * w3[k * 128 + j];
        u0[h][j] = acc;
        __syncthreads();
        float acc2 = 0.f;
        #pragma unroll 8
        for (int l = 0; l < 128; ++l) acc2 += u0[h][l] * w2[l * 128 + j];
        Wboth[i * 128 + j] = acc2;
    } else if (b < 128) {               // X rows
        const int i = 2 * (b - 64) + h;
        float acc = 0.f;
        #pragma unroll 8
        for (int k = 0; k < 128; ++k) acc += w1[i * 128 + k] * w4[k * 128 + j];
        u0[h][j] = acc;
        __syncthreads();
        float acc2 = 0.f;
        #pragma unroll 8
        for (int k = 0; k < 128; ++k) acc2 += u0[h][k] * w3[k * 128 + j];
        u1[h][j] = acc2;
        __syncthreads();
        float acc3 = 0.f;
        #pragma unroll 8
        for (int l = 0; l < 128; ++l) acc3 += u1[h][l] * w2[l * 128 + j];
        Wboth[(128 + i) * 128 + j] = acc3;
    } else if (b == 128) {              // bias chain (3 sequential vec-mats)
        if (t < 128) {
            float a3 = b3[t];
            #pragma unroll 8
            for (int k = 0; k < 128; ++k) a3 += w3[t * 128 + k] * b2[k];
            u0[0][t] = a3;
        }
        __syncthreads();
        if (t < 128) {
            float a4 = b4[t];
            #pragma unroll 8
            for (int k = 0; k < 128; ++k) a4 += w4[t * 128 + k] * u0[0][k];
            u1[0][t] = a4;
            bboth[t] = a4;              // bg
        }
        __syncthreads();
        if (t < 128) {
            float ax = b1[t];
            #pragma unroll 8
            for (int k = 0; k < 128; ++k) ax += w1[t * 128 + k] * u1[0][k];
            bboth[128 + t] = ax;        // bx
        }
    } else {                            // zero fn2/mag/total/donecnt (3328 floats)
        #pragma unroll
        for (int s = 0; s < 13; ++s) zeros[t + 256 * s] = 0.f;
    }
}

// ---------------- K1: 256-block MFMA gemm Y = f @ Wb^T + bboth; xb, fn2, mag --------
__global__ __launch_bounds__(256) void k_gemm2(
    const float* __restrict__ f, const float* __restrict__ Wb,
    const float* __restrict__ bb,
    unsigned short* __restrict__ xb, float* __restrict__ fn2, float* __restrict__ mag)
{
    const int b = blockIdx.x, t = threadIdx.x;
    const int wave = t >> 6, lane = t & 63;
    const int l15 = lane & 15, quad = lane >> 4;
    const int i0 = (b >> 4) * 64;       // 16 row-tiles of 64
    const int j0 = (b & 15) * 16;       // 16 col-tiles of 16 (over 256 outputs)
    const int ri = i0 + wave * 16;
    const float* ap = f  + (ri + l15) * 128 + quad * 8;
    const float* bp = Wb + (j0 + l15) * 128 + quad * 8;
    v4f acc = {0.f, 0.f, 0.f, 0.f};
    #pragma unroll
    for (int kc = 0; kc < 4; ++kc) {
        v8s a   = cvt8(ap + kc * 32);
        v8s bbv = cvt8(bp + kc * 32);
        acc = __builtin_amdgcn_mfma_f32_16x16x32_bf16(a, bbv, acc, 0, 0, 0);
    }
    const float bias = bb[j0 + l15];
    const bool isx = (j0 >= 128);
    float sq[4];
    #pragma unroll
    for (int reg = 0; reg < 4; ++reg) {
        float yv = acc[reg] + bias;
        sq[reg] = yv * yv;
        if (isx) xb[(ri + quad * 4 + reg) * DIM + (j0 - 128) + l15] = f2bf(yv);
    }
    #pragma unroll
    for (int reg = 0; reg < 4; ++reg) {
        float ss = sq[reg];
        ss += __shfl_xor(ss, 1, 64); ss += __shfl_xor(ss, 2, 64);
        ss += __shfl_xor(ss, 4, 64); ss += __shfl_xor(ss, 8, 64);
        if (l15 == 0)
            atomicAdd((isx ? mag : fn2) + (ri + quad * 4 + reg), ss);
    }
}

// ---------------- K2: 256-block affinity -> Bu (UNSCALED bf16), totals, A0 ----------
__global__ __launch_bounds__(256) void k_aff(
    const unsigned short* __restrict__ xb, const float* __restrict__ mag,
    const float* __restrict__ fn2,
    unsigned short* __restrict__ Bu, float* __restrict__ A0,
    float* __restrict__ total)
{
    const int b = blockIdx.x, t = threadIdx.x;
    const int wave = t >> 6, lane = t & 63;
    const int l15 = lane & 15, quad = lane >> 4;
    const int slab = b >> 2;            // rows slab*16..+16
    const int qtr  = b & 3;             // j-quarter (256 cols)
    const int i0 = slab * 16;

    const unsigned short* ap = xb + (i0 + l15) * DIM + quad * 8;
    v8s afr[4];
    #pragma unroll
    for (int kc = 0; kc < 4; ++kc) afr[kc] = *(const v8s*)(ap + kc * 32);

    float rowsum[4] = {0.f, 0.f, 0.f, 0.f};
    #pragma unroll
    for (int s = 0; s < 4; ++s) {
        const int j0 = (qtr * 16 + wave * 4 + s) * 16;
        const unsigned short* bp = xb + (j0 + l15) * DIM + quad * 8;
        v4f acc = {0.f, 0.f, 0.f, 0.f};
        #pragma unroll
        for (int kc = 0; kc < 4; ++kc)
            acc = __builtin_amdgcn_mfma_f32_16x16x32_bf16(
                      afr[kc], *(const v8s*)(bp + kc * 32), acc, 0, 0, 0);
        const int gj = j0 + l15;
        const float rm = 1.0f / mag[gj];
        const float fj = fn2[gj] * INV2SIG2;
        #pragma unroll
        for (int reg = 0; reg < 4; ++reg) {
            const int gi = i0 + quad * 4 + reg;
            float Sv = acc[reg] * rm - 1.0f;
            float a = (gi == gj) ? 0.f : __expf(-(Sv * Sv) * fj);
            Bu[gi * N + gj] = f2bf(a);
            rowsum[reg] += a;
            if (gi == 0) A0[gj] = a;    // fp32 row 0 for P0
        }
    }
    #pragma unroll
    for (int reg = 0; reg < 4; ++reg) {
        float ss = rowsum[reg];
        ss += __shfl_xor(ss, 1, 64); ss += __shfl_xor(ss, 2, 64);
        ss += __shfl_xor(ss, 4, 64); ss += __shfl_xor(ss, 8, 64);
        if (l15 == 0) atomicAdd(&total[i0 + quad * 4 + reg], ss);
    }
}

// ---------------- K5: v[r] = P0[r] + rscale*(Bu z)[r]; last launch fuses the
//                  Aitken+softmax epilogue in the last-arriving block ----------
__global__ __launch_bounds__(256) void k_mvb2(
    const unsigned short* __restrict__ M, const float* __restrict__ A0,
    const float* __restrict__ total,
    const float* __restrict__ z, float* __restrict__ v, int first,
    int fin, const float* __restrict__ zM1, const float* __restrict__ zM2,
    unsigned int* donecnt, float* __restrict__ out)
{
    __shared__ float red4[4];
    __shared__ float bvalS;
    __shared__ float ush[1024];
    __shared__ int winner;
    const int t = threadIdx.x;
    const int wave = t >> 6, lane = t & 63;
    const int r = blockIdx.x * 4 + wave;
    const float r0s = 1.0f / fmaxf(total[0], 1e-10f);
    const float rscale = (r == 0) ? 0.f : LAMB / fmaxf(total[r], 1e-10f);
    const float p0r    = (r == 0) ? 0.f : A0[r] * r0s;
    const float zscale = first ? r0s : 1.0f;

    const uint4* m4 = (const uint4*)(M + r * N + lane * 16);
    const float4* z4 = (const float4*)(z + lane * 16);
    uint4 ma = m4[0], mb = m4[1];
    float4 z0 = z4[0], z1 = z4[1], z2 = z4[2], z3 = z4[3];
    float acc = 0.f;
    acc += bf2f((unsigned short)(ma.x)) * z0.x + bf2f((unsigned short)(ma.x >> 16)) * z0.y;
    acc += bf2f((unsigned short)(ma.y)) * z0.z + bf2f((unsigned short)(ma.y >> 16)) * z0.w;
    acc += bf2f((unsigned short)(ma.z)) * z1.x + bf2f((unsigned short)(ma.z >> 16)) * z1.y;
    acc += bf2f((unsigned short)(ma.w)) * z1.z + bf2f((unsigned short)(ma.w >> 16)) * z1.w;
    acc += bf2f((unsigned short)(mb.x)) * z2.x + bf2f((unsigned short)(mb.x >> 16)) * z2.y;
    acc += bf2f((unsigned short)(mb.y)) * z2.z + bf2f((unsigned short)(mb.y >> 16)) * z2.w;
    acc += bf2f((unsigned short)(mb.z)) * z3.x + bf2f((unsigned short)(mb.z >> 16)) * z3.y;
    acc += bf2f((unsigned short)(mb.w)) * z3.z + bf2f((unsigned short)(mb.w >> 16)) * z3.w;
    #pragma unroll
    for (int off = 32; off >= 1; off >>= 1) acc += __shfl_xor(acc, off, 64);
    if (lane == 0) v[r] = p0r + rscale * zscale * acc;

    if (!fin) return;
    // last-block-done: one release RMW per block (NOT a spin — rounds 9/10
    // showed spinning costs ~15us/barrier; a single arrival add is cheap).
    __syncthreads();
    if (t == 0) {
        __threadfence();
        unsigned int old = atomicAdd(donecnt, 1u);
        winner = (old == 255u) ? 1 : 0;
        if (winner) __threadfence();
    }
    __syncthreads();
    if (!winner) return;

    // ---- 256-thread epilogue (verified in rounds 9/10): zM = v ----
    const float* zM = v;
    float av[4], d1v[4];
    float s12 = 0.f, s22 = 0.f;
    #pragma unroll
    for (int k = 0; k < 4; ++k) {
        const int e = t + 256 * k;
        av[k] = zM[e];
        float bb = zM1[e], cc = zM2[e];
        d1v[k] = av[k] - bb;
        float d2 = bb - cc;
        s12 += d1v[k] * d2;
        s22 += d2 * d2;
    }
    #pragma unroll
    for (int off = 32; off >= 1; off >>= 1) s12 += __shfl_down(s12, off, 64);
    if (lane == 0) red4[wave] = s12;
    __syncthreads();
    if (t == 0) bvalS = red4[0] + red4[1] + red4[2] + red4[3];
    __syncthreads();
    const float dot12 = bvalS;
    __syncthreads();
    #pragma unroll
    for (int off = 32; off >= 1; off >>= 1) s22 += __shfl_down(s22, off, 64);
    if (lane == 0) red4[wave] = s22;
    __syncthreads();
    if (t == 0) bvalS = red4[0] + red4[1] + red4[2] + red4[3];
    __syncthreads();
    const float dot22 = bvalS;
    __syncthreads();

    float lam = dot12 / fmaxf(dot22, 1e-30f);
    lam = fminf(fmaxf(lam, 0.0f), 0.95f);
    const float coef = lam / (1.0f - lam);
    #pragma unroll
    for (int k = 0; k < 4; ++k) ush[t + 256 * k] = av[k] + coef * d1v[k];
    __syncthreads();

    float Pv[4];
    float ps = 0.f;
    #pragma unroll
    for (int k = 0; k < 4; ++k) {
        const int e = t + 256 * k;
        Pv[k] = (e >= 1) ? 0.1f * ush[e] : 0.f;
        ps += Pv[k];
    }
    #pragma unroll
    for (int off = 32; off >= 1; off >>= 1) ps += __shfl_down(ps, off, 64);
    if (lane == 0) red4[wave] = ps;
    __syncthreads();
    if (t == 0) bvalS = (red4[0] + red4[1] + red4[2] + red4[3]) / 1023.0f;
    __syncthreads();
    const float mean = bvalS;
    __syncthreads();

    float mx = 0.f;   // relu'd values >= 0
    #pragma unroll
    for (int k = 0; k < 4; ++k) {
        const int e = t + 256 * k;
        if (e >= 1) {
            Pv[k] = fmaxf(Pv[k] - mean, 0.f) * 100.f;
            mx = fmaxf(mx, Pv[k]);
        }
    }
    #pragma unroll
    for (int off = 32; off >= 1; off >>= 1) mx = fmaxf(mx, __shfl_down(mx, off, 64));
    if (lane == 0) red4[wave] = mx;
    __syncthreads();
    if (t == 0) bvalS = fmaxf(fmaxf(red4[0], red4[1]), fmaxf(red4[2], red4[3]));
    __syncthreads();
    const float gmax = bvalS;
    __syncthreads();

    float Ev[4];
    float es = 0.f;
    #pragma unroll
    for (int k = 0; k < 4; ++k) {
        const int e = t + 256 * k;
        Ev[k] = (e >= 1) ? expf(Pv[k] - gmax) : 0.f;
        es += Ev[k];
    }
    #pragma unroll
    for (int off = 32; off >= 1; off >>= 1) es += __shfl_down(es, off, 64);
    if (lane == 0) red4[wave] = es;
    __syncthreads();
    if (t == 0) bvalS = red4[0] + red4[1] + red4[2] + red4[3];
    __syncthreads();
    const float esum = bvalS;
    #pragma unroll
    for (int k = 0; k < 4; ++k) {
        const int e = t + 256 * k;
        if (e >= 1) out[e - 1] = Ev[k] / esum;
    }
}

extern "C" void kernel_launch(void* const* d_in, const int* in_sizes, int n_in,
                              void* d_out, int out_size, void* d_ws, size_t ws_size,
                              hipStream_t stream) {
    const float* f  = (const float*)d_in[0];
    const float* w1 = (const float*)d_in[1];
    const float* b1 = (const float*)d_in[2];
    const float* w2 = (const float*)d_in[3];
    const float* b2 = (const float*)d_in[4];
    const float* w3 = (const float*)d_in[5];
    const float* b3 = (const float*)d_in[6];
    const float* w4 = (const float*)d_in[7];
    const float* b4 = (const float*)d_in[8];
    float* ws = (float*)d_ws;

    // float-unit offsets
    float* Wboth = ws;                                   // 32768
    float* bboth = ws + 32768;                           // 256
    float* fn2   = ws + 33024;                           // 1024  (fn2/mag/total/donecnt
    float* mag   = ws + 34048;                           //  contiguous, zeroed together)
    float* total = ws + 35072;                           // 1024
    unsigned int* donecnt = (unsigned int*)(ws + 36096); // 256-float pad
    float* A0    = ws + 36352;                           // 1024
    float* zb0   = ws + 37376;                           // 1024
    float* zb1   = ws + 38400;                           // 1024
    float* zb2   = ws + 39424;                           // 1024
    unsigned short* xb = (unsigned short*)(ws + 40448);  // 65536 floats
    unsigned short* Bu = (unsigned short*)(ws + 105984); // 524288 floats
    float* out = (float*)d_out;

    k_compose<<<130, 256, 0, stream>>>(w1, w2, w3, w4, b1, b2, b3, b4,
                                       Wboth, bboth, fn2);
    k_gemm2<<<256, 256, 0, stream>>>(f, Wboth, bboth, xb, fn2, mag);
    k_aff<<<256, 256, 0, stream>>>(xb, mag, fn2, Bu, A0, total);

    // Neumann chain, 3 steps; it0 consumes fp32 A0 with folded 1/total0;
    // it2 fuses the epilogue via last-block-done.
    k_mvb2<<<256, 256, 0, stream>>>(Bu, A0, total, A0,  zb0, 1, 0,
                                    nullptr, nullptr, donecnt, out);
    k_mvb2<<<256, 256, 0, stream>>>(Bu, A0, total, zb0, zb1, 0, 0,
                                    nullptr, nullptr, donecnt, out);
    k_mvb2<<<256, 256, 0, stream>>>(Bu, A0, total, zb1, zb2, 0, 1,
                                    zb1, zb0, donecnt, out);
}